// Round 1
// 189.673 us; speedup vs baseline: 1.0653x; 1.0653x over previous
//
#include <hip/hip_runtime.h>
#include <hip/hip_bf16.h>

// Problem: B=2, LQ=2048, LK=4096, D_MODEL=512, NHEAD=8, D_HEAD=64
// Round 6: barrier-free, LDS-free attention via swapped QK^T (S^T = K@Q^T in
// 32x32x16 MFMA), in-register softmax (no-max: scores bounded, masked g=-1e30),
// cvt_pk_bf16 + permlane32_swap P redistribution, fragment-major K/V layouts
// written by the projection epilogue for fully coalesced fragment loads.

using bf16   = __hip_bfloat16;
using bf16x8 = __attribute__((ext_vector_type(8))) short;  // 8 bf16 = 4 VGPRs
using f32x4  = __attribute__((ext_vector_type(4))) float;
using f32x16 = __attribute__((ext_vector_type(16))) float;
using uint4v = __attribute__((ext_vector_type(4))) unsigned int;

#define MFMA16(a, b, c) __builtin_amdgcn_mfma_f32_16x16x32_bf16((a), (b), (c), 0, 0, 0)
#define MFMA32(a, b, c) __builtin_amdgcn_mfma_f32_32x32x16_bf16((a), (b), (c), 0, 0, 0)

__device__ __forceinline__ bf16x8 load8(const bf16* p) {
    return *reinterpret_cast<const bf16x8*>(p);
}
__device__ __forceinline__ short f2bf(float x) {
    bf16 h = __float2bfloat16(x);
    return *reinterpret_cast<short*>(&h);
}

// ---------------------------------------------------------------------------
// merged fp32->bf16 converts
// ---------------------------------------------------------------------------
__global__ void cvt_x(const float* __restrict__ q, const float* __restrict__ kv,
                      bf16* __restrict__ qb, bf16* __restrict__ kvb) {
    int i = blockIdx.x * blockDim.x + threadIdx.x;   // 0..1572863
    const float* src; bf16* dst; int j;
    if (i < 524288) { src = q;  dst = qb;  j = i; }
    else            { src = kv; dst = kvb; j = i - 524288; }
    float4 v = reinterpret_cast<const float4*>(src)[j];
    ushort4 o;
    o.x = (unsigned short)f2bf(v.x);
    o.y = (unsigned short)f2bf(v.y);
    o.z = (unsigned short)f2bf(v.z);
    o.w = (unsigned short)f2bf(v.w);
    reinterpret_cast<ushort4*>(dst)[j] = o;
}

__global__ void cvt_w(const float* __restrict__ a, const float* __restrict__ b,
                      const float* __restrict__ c, const float* __restrict__ d,
                      bf16* __restrict__ oa, bf16* __restrict__ ob,
                      bf16* __restrict__ oc, bf16* __restrict__ od) {
    int i = blockIdx.x * blockDim.x + threadIdx.x;   // 0..262143
    int t = i >> 16, j = i & 65535;
    const float* src = (t == 0) ? a : (t == 1) ? b : (t == 2) ? c : d;
    bf16*        dst = (t == 0) ? oa : (t == 1) ? ob : (t == 2) ? oc : od;
    float4 v = reinterpret_cast<const float4*>(src)[j];
    ushort4 o;
    o.x = (unsigned short)f2bf(v.x);
    o.y = (unsigned short)f2bf(v.y);
    o.z = (unsigned short)f2bf(v.z);
    o.w = (unsigned short)f2bf(v.w);
    reinterpret_cast<ushort4*>(dst)[j] = o;
}

// ---------------------------------------------------------------------------
// g2[b][k] = mask ? log2(max(gate, 1e-6)) : -1e30   (log2 so attn uses exp2)
// ---------------------------------------------------------------------------
__global__ void prep_gate_kernel(const float* __restrict__ gate,
                                 const int* __restrict__ mask,
                                 float* __restrict__ g, int n) {
    int i = blockIdx.x * blockDim.x + threadIdx.x;
    if (i < n) {
        float gv = fmaxf(gate[i], 1e-6f);
        g[i] = mask[i] ? log2f(gv) : -1e30f;
    }
}

// ---------------------------------------------------------------------------
// Projection body: C = X @ W^T + bias. X:[M,512] bf16, W bf16 row-major.
// mode 0: fp32 row-major [M,512]
// mode 1: bf16 per-head   [(b*8+h)*L + i]*64 + dh            (Q)
// mode 3: bf16 K fragment-major: for key k, d=dh:
//         ((bh*128 + k>>5)*4 + dh>>4)*512 + ((dh>>3)&1)*256 + (k&31)*8 + (dh&7)
//         -> attn A-frag load (lane l) is contiguous 1KB per (tile, d-slice)
// mode 4: bf16 V fragment-major: for key k, d=dh:
//         (((bh*128 + k>>5)*2 + dh>>5)*2 + (k>>4)&1)*512 + ((k>>3)&1)*256
//            + (dh&31)*8 + (k&7)
// ---------------------------------------------------------------------------
__device__ __forceinline__ void proj_body(const bf16* __restrict__ X,
                                          const bf16* __restrict__ W,
                                          const float* __restrict__ bias,
                                          void* __restrict__ Cout,
                                          int mode, int L, int mb, bf16* Ws) {
    const int tid  = threadIdx.x;
    const int wave = tid >> 6;
    const int lane = tid & 63;
    const int li   = lane & 15;
    const int quad = lane >> 4;
    const int n0   = blockIdx.x * 64;
    const int m0   = mb * 128 + wave * 32;

    f32x4 zero = {0.f, 0.f, 0.f, 0.f};
    f32x4 acc[2][4];
    for (int mt = 0; mt < 2; ++mt)
        for (int t = 0; t < 4; ++t) acc[mt][t] = zero;

    const bf16* x0 = X + (size_t)(m0 + li) * 512;
    const bf16* x1 = X + (size_t)(m0 + 16 + li) * 512;

    for (int p = 0; p < 2; ++p) {
        __syncthreads();
        for (int i = 0; i < 8; ++i) {        // stage 64 x 256 W block
            const int c  = i * 256 + tid;
            const int cr = c >> 5;
            const int kc = (c & 31) * 8;
            *reinterpret_cast<bf16x8*>(&Ws[cr * 264 + kc]) =
                load8(W + (size_t)(n0 + cr) * 512 + p * 256 + kc);
        }
        __syncthreads();

        for (int k0 = 0; k0 < 256; k0 += 32) {
            bf16x8 a0 = load8(x0 + p * 256 + k0 + quad * 8);
            bf16x8 a1 = load8(x1 + p * 256 + k0 + quad * 8);
            for (int t = 0; t < 4; ++t) {
                bf16x8 w8 = load8(&Ws[(t * 16 + li) * 264 + k0 + quad * 8]);
                acc[0][t] = MFMA16(a0, w8, acc[0][t]);
                acc[1][t] = MFMA16(a1, w8, acc[1][t]);
            }
        }
    }

    for (int t = 0; t < 4; ++t) {
        const int col = n0 + t * 16 + li;
        const float bcol = bias[col];
        for (int mt = 0; mt < 2; ++mt) {
            for (int r = 0; r < 4; ++r) {
                const int row = m0 + mt * 16 + quad * 4 + r;   // C-layout
                const float v = acc[mt][t][r] + bcol;
                if (mode == 0) {
                    ((float*)Cout)[(size_t)row * 512 + col] = v;
                } else {
                    const int bb2 = row / L;
                    const int i   = row - bb2 * L;
                    const int hh  = col >> 6;
                    const int dh  = col & 63;
                    const int bh  = bb2 * 8 + hh;
                    size_t idx;
                    if (mode == 1) {
                        idx = ((size_t)bh * L + i) * 64 + dh;
                    } else if (mode == 3) {
                        idx = ((((size_t)bh * 128 + (i >> 5)) * 4 + (dh >> 4)) * 64
                               + ((dh >> 3) & 1) * 32 + (i & 31)) * 8 + (dh & 7);
                    } else {  // mode 4
                        idx = (((((size_t)bh * 128 + (i >> 5)) * 2 + (dh >> 5)) * 2
                               + ((i >> 4) & 1)) * 64 + ((i >> 3) & 1) * 32 + (dh & 31)) * 8
                              + (i & 7);
                    }
                    ((bf16*)Cout)[idx] = __float2bfloat16(v);
                }
            }
        }
    }
}

// Fused Q/K/V projections: grid (8, 160). y<32: Q; y<96: K; else V.
__global__ void proj_qkv(const bf16* __restrict__ qb, const bf16* __restrict__ kvb,
                         const bf16* __restrict__ Wq, const float* __restrict__ bq,
                         const bf16* __restrict__ Wk, const float* __restrict__ bk,
                         const bf16* __restrict__ Wv, const float* __restrict__ bv,
                         bf16* __restrict__ qp, bf16* __restrict__ kf,
                         bf16* __restrict__ vf) {
    __shared__ alignas(16) bf16 Ws[64 * 264];
    const int my = blockIdx.y;
    if (my < 32)      proj_body(qb,  Wq, bq, qp, 1, 2048, my,      Ws);
    else if (my < 96) proj_body(kvb, Wk, bk, kf, 3, 4096, my - 32, Ws);
    else              proj_body(kvb, Wv, bv, vf, 4, 4096, my - 96, Ws);
}

// Output projection: grid (8, 32), fp32 out.
__global__ void proj_o(const bf16* __restrict__ op, const bf16* __restrict__ Wo,
                       const float* __restrict__ bo, float* __restrict__ out) {
    __shared__ alignas(16) bf16 Ws[64 * 264];
    proj_body(op, Wo, bo, out, 0, 1, blockIdx.y, Ws);
}

// ---------------------------------------------------------------------------
// Barrier-free K-split flash attention, swapped-operand QK^T, no LDS.
// Grid 512 = b(2) x h(8) x qt(8 tiles of 256 rows) x sp(4 K-splits of 1024).
// Block 256 thr = 4 waves; wave owns 64 q-rows (2 sub-tiles of 32).
// Per 32-key tile:
//   S^T(32k x 32q) = sum_ds mfma32(Kfrag[ds], Qfrag[ds])  -- lane holds
//     P-row slice: q = lane&31, k = (r&3)+8*(r>>2)+4*(lane>>5)
//   P = exp2(S*log2e/8 + log2gate) in-register; bf16 pack via v_cvt_pk,
//   redistribute across lane halves with v_permlane32_swap -> PV A-frags.
//   O(32q x 64d) += P @ V via 8 mfma32 with fragment-major V loads.
// Writes UNNORMALIZED fp32 partial O + fp32 l for the combine.
// ---------------------------------------------------------------------------
__global__ __launch_bounds__(256, 2)
void attn_kernel(const bf16* __restrict__ qp, const bf16* __restrict__ kf,
                 const bf16* __restrict__ vf, const float* __restrict__ g2,
                 float* __restrict__ Opart, float* __restrict__ lpart) {
    const int tid  = threadIdx.x;
    const int wave = tid >> 6;
    const int lane = tid & 63;
    const int ql   = lane & 31;
    const int hi   = lane >> 5;

    const int bx = blockIdx.x;
    const int sp = bx & 3;
    const int qt = (bx >> 2) & 7;
    const int h  = (bx >> 5) & 7;
    const int b  = bx >> 8;
    const int bh = b * 8 + h;
    const int q0 = qt * 256 + wave * 64;

    // Q B-fragments: bq[sub][ds]: lane holds Q[q0+sub*32+ql][ds*16 + hi*8 + j]
    bf16x8 bq[2][4];
    const bf16* qb = qp + ((size_t)bh * 2048 + q0 + ql) * 64 + hi * 8;
    #pragma unroll
    for (int sub = 0; sub < 2; ++sub)
        #pragma unroll
        for (int ds = 0; ds < 4; ++ds)
            bq[sub][ds] = load8(qb + sub * 2048 + ds * 16);

    f32x16 od[2][2];
    #pragma unroll
    for (int sub = 0; sub < 2; ++sub)
        #pragma unroll
        for (int t = 0; t < 2; ++t)
            #pragma unroll
            for (int r = 0; r < 16; ++r) od[sub][t][r] = 0.f;
    float lsum[2] = {0.f, 0.f};

    // fragment-major bases: per-32-key-tile stride = 2048 bf16 (4KB)
    const bf16* kbase = kf + (size_t)bh * 262144 + (size_t)sp * 65536 + lane * 8;
    const bf16* vbase = vf + (size_t)bh * 262144 + (size_t)sp * 65536 + lane * 8;
    const float* gbase = g2 + (size_t)b * 4096 + sp * 1024 + hi * 4;

    const float SC = 0.18033688011112042f;   // log2(e) / 8

    // prefetched K fragments for tile 0
    bf16x8 ka0 = load8(kbase);
    bf16x8 ka1 = load8(kbase + 512);
    bf16x8 ka2 = load8(kbase + 1024);
    bf16x8 ka3 = load8(kbase + 1536);

    for (int kt = 0; kt < 32; ++kt) {
        // issue V fragments + gate loads early (consumed after softmax)
        const bf16* vp = vbase + (size_t)kt * 2048;
        bf16x8 bv00 = load8(vp);             // (d-tile 0, k-slot 0)
        bf16x8 bv01 = load8(vp + 512);       // (d-tile 0, k-slot 1)
        bf16x8 bv10 = load8(vp + 1024);      // (d-tile 1, k-slot 0)
        bf16x8 bv11 = load8(vp + 1536);      // (d-tile 1, k-slot 1)
        const float* gp = gbase + kt * 32;
        f32x4 gv0 = *(const f32x4*)(gp);
        f32x4 gv1 = *(const f32x4*)(gp + 8);
        f32x4 gv2 = *(const f32x4*)(gp + 16);
        f32x4 gv3 = *(const f32x4*)(gp + 24);
        float gl[16];
        #pragma unroll
        for (int c = 0; c < 4; ++c) {
            gl[c] = gv0[c]; gl[4 + c] = gv1[c]; gl[8 + c] = gv2[c]; gl[12 + c] = gv3[c];
        }

        bf16x8 pa[2][2];
        #pragma unroll
        for (int sub = 0; sub < 2; ++sub) {
            f32x16 sacc;
            #pragma unroll
            for (int r = 0; r < 16; ++r) sacc[r] = 0.f;
            sacc = MFMA32(ka0, bq[sub][0], sacc);
            sacc = MFMA32(ka1, bq[sub][1], sacc);
            sacc = MFMA32(ka2, bq[sub][2], sacc);
            sacc = MFMA32(ka3, bq[sub][3], sacc);

            float p[16];
            #pragma unroll
            for (int r = 0; r < 16; ++r)
                p[r] = __builtin_amdgcn_exp2f(fmaf(sacc[r], SC, gl[r]));

            // pack to bf16 pairs: w[g] = (p[2g] lo, p[2g+1] hi)
            unsigned w[8];
            #pragma unroll
            for (int i = 0; i < 8; ++i)
                asm("v_cvt_pk_bf16_f32 %0, %1, %2"
                    : "=v"(w[i]) : "v"(p[2 * i]), "v"(p[2 * i + 1]));

            // tree-reduce p into lsum (p dead after cvt)
            #pragma unroll
            for (int st = 1; st < 16; st <<= 1)
                #pragma unroll
                for (int r = 0; r < 16; r += 2 * st) p[r] += p[r + st];
            lsum[sub] += p[0];

            // redistribute halves: A-frag needs k = s*16 + hi*8 + j
            asm("v_permlane32_swap_b32 %0, %1" : "+v"(w[0]), "+v"(w[2]));
            asm("v_permlane32_swap_b32 %0, %1" : "+v"(w[1]), "+v"(w[3]));
            asm("v_permlane32_swap_b32 %0, %1" : "+v"(w[4]), "+v"(w[6]));
            asm("v_permlane32_swap_b32 %0, %1" : "+v"(w[5]), "+v"(w[7]));
            uint4v u0 = {w[0], w[1], w[2], w[3]};
            uint4v u1 = {w[4], w[5], w[6], w[7]};
            pa[sub][0] = __builtin_bit_cast(bf16x8, u0);
            pa[sub][1] = __builtin_bit_cast(bf16x8, u1);
        }

        // prefetch next K tile (clamped dummy on last iter)
        const int ktn = kt < 31 ? kt + 1 : 31;
        const bf16* kp_n = kbase + (size_t)ktn * 2048;
        bf16x8 kn0 = load8(kp_n);
        bf16x8 kn1 = load8(kp_n + 512);
        bf16x8 kn2 = load8(kp_n + 1024);
        bf16x8 kn3 = load8(kp_n + 1536);

        od[0][0] = MFMA32(pa[0][0], bv00, od[0][0]);
        od[0][0] = MFMA32(pa[0][1], bv01, od[0][0]);
        od[0][1] = MFMA32(pa[0][0], bv10, od[0][1]);
        od[0][1] = MFMA32(pa[0][1], bv11, od[0][1]);
        od[1][0] = MFMA32(pa[1][0], bv00, od[1][0]);
        od[1][0] = MFMA32(pa[1][1], bv01, od[1][0]);
        od[1][1] = MFMA32(pa[1][0], bv10, od[1][1]);
        od[1][1] = MFMA32(pa[1][1], bv11, od[1][1]);

        ka0 = kn0; ka1 = kn1; ka2 = kn2; ka3 = kn3;
    }

    // l: lane holds partial for q=ql over its k-half; fold halves
    float l0 = lsum[0] + __shfl_xor(lsum[0], 32);
    float l1 = lsum[1] + __shfl_xor(lsum[1], 32);

    // write fp32 partial O: Opart[(bh*2048 + q)*4 + sp]*64 + d
    float* ob = Opart + ((size_t)(bh * 2048 + q0) * 4 + sp) * 64;
    #pragma unroll
    for (int sub = 0; sub < 2; ++sub)
        #pragma unroll
        for (int t = 0; t < 2; ++t)
            #pragma unroll
            for (int r = 0; r < 16; ++r) {
                const int qq = sub * 32 + (r & 3) + 8 * (r >> 2) + hi * 4;
                ob[(size_t)qq * 256 + t * 32 + ql] = od[sub][t][r];
            }
    if (lane < 32) {
        lpart[((size_t)(bh * 2048 + q0 + lane)) * 4 + sp]      = l0;
        lpart[((size_t)(bh * 2048 + q0 + 32 + lane)) * 4 + sp] = l1;
    }
}

// ---------------------------------------------------------------------------
// Combine 4 K-split partials (plain sums; no max weights needed).
// Grid 512 x 256 thr; thread: row = gidx>>2 (= bh*2048+q), 16 cols at (gidx&3)*16.
// ---------------------------------------------------------------------------
__global__ void attn_combine(const float* __restrict__ Opart,
                             const float* __restrict__ lpart,
                             bf16* __restrict__ op) {
    const int gidx = blockIdx.x * 256 + threadIdx.x;  // 0..131071
    const int row  = gidx >> 2;                        // bh*2048 + q
    const int c0   = (gidx & 3) * 16;

    float acc[16];
    #pragma unroll
    for (int j = 0; j < 16; ++j) acc[j] = 0.f;
    float L = 0.f;
    for (int s = 0; s < 4; ++s) {
        const float* src = Opart + ((size_t)row * 4 + s) * 64 + c0;
        const float4 v0 = reinterpret_cast<const float4*>(src)[0];
        const float4 v1 = reinterpret_cast<const float4*>(src)[1];
        const float4 v2 = reinterpret_cast<const float4*>(src)[2];
        const float4 v3 = reinterpret_cast<const float4*>(src)[3];
        acc[0] += v0.x; acc[1] += v0.y; acc[2]  += v0.z; acc[3]  += v0.w;
        acc[4] += v1.x; acc[5] += v1.y; acc[6]  += v1.z; acc[7]  += v1.w;
        acc[8] += v2.x; acc[9] += v2.y; acc[10] += v2.z; acc[11] += v2.w;
        acc[12] += v3.x; acc[13] += v3.y; acc[14] += v3.z; acc[15] += v3.w;
        L += lpart[(size_t)row * 4 + s];
    }
    const float invL = 1.0f / L;

    const int bh = row >> 11;
    const int q  = row & 2047;
    const int bb = bh >> 3;
    const int hh = bh & 7;
    bf16* dst = op + ((size_t)bb * 2048 + q) * 512 + hh * 64 + c0;
    bf16x8 r0, r1;
    #pragma unroll
    for (int j = 0; j < 8; ++j) {
        r0[j] = f2bf(acc[j] * invL);
        r1[j] = f2bf(acc[8 + j] * invL);
    }
    *reinterpret_cast<bf16x8*>(dst)     = r0;
    *reinterpret_cast<bf16x8*>(dst + 8) = r1;
}

// ---------------------------------------------------------------------------
extern "C" void kernel_launch(void* const* d_in, const int* in_sizes, int n_in,
                              void* d_out, int out_size, void* d_ws, size_t ws_size,
                              hipStream_t stream) {
    const float* q    = (const float*)d_in[0];
    const float* kv   = (const float*)d_in[1];
    const float* gate = (const float*)d_in[2];
    const int*   mask = (const int*)d_in[3];
    const float* Wq = (const float*)d_in[4];  const float* bq = (const float*)d_in[5];
    const float* Wk = (const float*)d_in[6];  const float* bk = (const float*)d_in[7];
    const float* Wv = (const float*)d_in[8];  const float* bv = (const float*)d_in[9];
    const float* Wo = (const float*)d_in[10]; const float* bo = (const float*)d_in[11];
    float* out = (float*)d_out;

    // workspace (MiB offsets): g2@0, Wqb@1, Wkb@1.5, Wvb@2, Wob@2.5, qb@3(4),
    // kvb@7(8), qp@15(4), kf@19(8), vf@27(8), op@35(4),
    // Opart fp32 @39(32), lpart fp32 @71(0.5)  -> total ~72 MiB
    char* ws = (char*)d_ws;
    float* g2  = (float*)ws;
    bf16* Wqb  = (bf16*)(ws + (1u  << 20));
    bf16* Wkb  = (bf16*)(ws + (1u  << 20) + (512u << 10));
    bf16* Wvb  = (bf16*)(ws + (2u  << 20));
    bf16* Wob  = (bf16*)(ws + (2u  << 20) + (512u << 10));
    bf16* qb   = (bf16*)(ws + (3u  << 20));
    bf16* kvb  = (bf16*)(ws + (7u  << 20));
    bf16* qp   = (bf16*)(ws + (15u << 20));
    bf16* kf   = (bf16*)(ws + (19u << 20));
    bf16* vf   = (bf16*)(ws + (27u << 20));
    bf16* op   = (bf16*)(ws + (35u << 20));
    float* Opart = (float*)(ws + (39u << 20));
    float* lpart = (float*)(ws + (71u << 20));

    prep_gate_kernel<<<32, 256, 0, stream>>>(gate, mask, g2, 2 * 4096);
    cvt_x<<<6144, 256, 0, stream>>>(q, kv, qb, kvb);
    cvt_w<<<1024, 256, 0, stream>>>(Wq, Wk, Wv, Wo, Wqb, Wkb, Wvb, Wob);

    proj_qkv<<<dim3(8, 160), 256, 0, stream>>>(qb, kvb, Wqb, bq, Wkb, bk,
                                               Wvb, bv, qp, kf, vf);

    attn_kernel<<<512, 256, 0, stream>>>(qp, kf, vf, g2, Opart, lpart);
    attn_combine<<<512, 256, 0, stream>>>(Opart, lpart, op);

    proj_o<<<dim3(8, 32), 256, 0, stream>>>(op, Wob, bo, out);
}

// Round 2
// 178.979 us; speedup vs baseline: 1.1290x; 1.0598x over previous
//
#include <hip/hip_runtime.h>
#include <hip/hip_bf16.h>

// Problem: B=2, LQ=2048, LK=4096, D_MODEL=512, NHEAD=8, D_HEAD=64
// Round 7: 5 launches (fused cvt/prep); XCD-grouped swizzles for attn + proj
// (K/V and X/W re-reads become same-XCD L2 hits); attn K-prefetch hoisted
// before softmax + s_setprio around MFMA; proj epilogue stages wave tiles
// through LDS for fully coalesced bf16x8 stores (was 32x scalar 2B scatter).

using bf16   = __hip_bfloat16;
using bf16x8 = __attribute__((ext_vector_type(8))) short;  // 8 bf16 = 4 VGPRs
using f32x4  = __attribute__((ext_vector_type(4))) float;
using f32x16 = __attribute__((ext_vector_type(16))) float;
using uint4v = __attribute__((ext_vector_type(4))) unsigned int;

#define MFMA16(a, b, c) __builtin_amdgcn_mfma_f32_16x16x32_bf16((a), (b), (c), 0, 0, 0)
#define MFMA32(a, b, c) __builtin_amdgcn_mfma_f32_32x32x16_bf16((a), (b), (c), 0, 0, 0)

__device__ __forceinline__ bf16x8 load8(const bf16* p) {
    return *reinterpret_cast<const bf16x8*>(p);
}
__device__ __forceinline__ unsigned short f2bf(float x) {
    bf16 h = __float2bfloat16(x);
    return *reinterpret_cast<unsigned short*>(&h);
}

// ---------------------------------------------------------------------------
// One fused prep kernel: q/kv -> bf16, 4 weight matrices -> bf16,
// gate+mask -> g2 (log2 domain). Exact grid: 7176 x 256.
// unit i: [0,524288) q f4 | [.,1572864) kv f4 | [.,1835008) weights f4
//         | [.,1837056) gate f4
// ---------------------------------------------------------------------------
__global__ void cvt_all(const float* __restrict__ q, const float* __restrict__ kv,
                        const float* __restrict__ Wq, const float* __restrict__ Wk,
                        const float* __restrict__ Wv, const float* __restrict__ Wo,
                        const float* __restrict__ gate, const int* __restrict__ mask,
                        bf16* __restrict__ qb, bf16* __restrict__ kvb,
                        bf16* __restrict__ Wqb, bf16* __restrict__ Wkb,
                        bf16* __restrict__ Wvb, bf16* __restrict__ Wob,
                        float* __restrict__ g2) {
    const int i = blockIdx.x * 256 + threadIdx.x;
    if (i < 1835008) {
        const float* src; bf16* dst; int j;
        if (i < 524288)       { src = q;  dst = qb;  j = i; }
        else if (i < 1572864) { src = kv; dst = kvb; j = i - 524288; }
        else {
            const int i2 = i - 1572864;
            const int t = i2 >> 16; j = i2 & 65535;
            src = (t == 0) ? Wq : (t == 1) ? Wk : (t == 2) ? Wv : Wo;
            dst = (t == 0) ? Wqb : (t == 1) ? Wkb : (t == 2) ? Wvb : Wob;
        }
        float4 v = reinterpret_cast<const float4*>(src)[j];
        ushort4 o;
        o.x = f2bf(v.x); o.y = f2bf(v.y); o.z = f2bf(v.z); o.w = f2bf(v.w);
        reinterpret_cast<ushort4*>(dst)[j] = o;
    } else {
        const int u = i - 1835008;                     // 0..2047
        float4 gv = reinterpret_cast<const float4*>(gate)[u];
        int4   mv = reinterpret_cast<const int4*>(mask)[u];
        float4 o;
        o.x = mv.x ? log2f(fmaxf(gv.x, 1e-6f)) : -1e30f;
        o.y = mv.y ? log2f(fmaxf(gv.y, 1e-6f)) : -1e30f;
        o.z = mv.z ? log2f(fmaxf(gv.z, 1e-6f)) : -1e30f;
        o.w = mv.w ? log2f(fmaxf(gv.w, 1e-6f)) : -1e30f;
        reinterpret_cast<float4*>(g2)[u] = o;
    }
}

// ---------------------------------------------------------------------------
// Projection body: C = X @ W^T + bias. X:[M,512] bf16, W bf16 row-major.
// mode 0: fp32 row-major [M,512] (direct stores, 64B segments)
// mode 1: bf16 per-head   [(b*8+h)*L + i]*64 + dh            (Q)
// mode 3: bf16 K fragment-major (matches attn A-frag reads)
// mode 4: bf16 V fragment-major (matches attn B-frag reads)
// bf16 modes: wave output tile (32 rows x 64 cols) is CONTIGUOUS 4KB in the
// output layout -> stage through LDS, store as 4x coalesced bf16x8 per lane.
// ---------------------------------------------------------------------------
__device__ __forceinline__ void proj_body(const bf16* __restrict__ X,
                                          const bf16* __restrict__ W,
                                          const float* __restrict__ bias,
                                          void* __restrict__ Cout,
                                          int mode, int L, int mb, int nb,
                                          bf16* Ws) {
    const int tid  = threadIdx.x;
    const int wave = tid >> 6;
    const int lane = tid & 63;
    const int li   = lane & 15;
    const int quad = lane >> 4;
    const int n0   = nb * 64;
    const int m0   = mb * 128 + wave * 32;

    f32x4 zero = {0.f, 0.f, 0.f, 0.f};
    f32x4 acc[2][4];
    for (int mt = 0; mt < 2; ++mt)
        for (int t = 0; t < 4; ++t) acc[mt][t] = zero;

    const bf16* x0 = X + (size_t)(m0 + li) * 512;
    const bf16* x1 = X + (size_t)(m0 + 16 + li) * 512;

    for (int p = 0; p < 2; ++p) {
        __syncthreads();
        for (int i = 0; i < 8; ++i) {        // stage 64 x 256 W block
            const int c  = i * 256 + tid;
            const int cr = c >> 5;
            const int kc = (c & 31) * 8;
            *reinterpret_cast<bf16x8*>(&Ws[cr * 264 + kc]) =
                load8(W + (size_t)(n0 + cr) * 512 + p * 256 + kc);
        }
        __syncthreads();

        for (int k0 = 0; k0 < 256; k0 += 32) {
            bf16x8 a0 = load8(x0 + p * 256 + k0 + quad * 8);
            bf16x8 a1 = load8(x1 + p * 256 + k0 + quad * 8);
            for (int t = 0; t < 4; ++t) {
                bf16x8 w8 = load8(&Ws[(t * 16 + li) * 264 + k0 + quad * 8]);
                acc[0][t] = MFMA16(a0, w8, acc[0][t]);
                acc[1][t] = MFMA16(a1, w8, acc[1][t]);
            }
        }
    }

    if (mode == 0) {
        // fp32 row-major direct: per store, 4 quad-rows x 64B contiguous
        for (int t = 0; t < 4; ++t) {
            const int col = n0 + t * 16 + li;
            const float bcol = bias[col];
            for (int mt = 0; mt < 2; ++mt)
                for (int r = 0; r < 4; ++r) {
                    const int row = m0 + mt * 16 + quad * 4 + r;
                    ((float*)Cout)[(size_t)row * 512 + col] = acc[mt][t][r] + bcol;
                }
        }
    } else {
        __syncthreads();                       // Ws no longer needed as W tile
        bf16* slab = Ws + wave * 2048;         // wave's 4KB staging slice
        #pragma unroll
        for (int t = 0; t < 4; ++t) {
            const float bcol = bias[n0 + t * 16 + li];
            #pragma unroll
            for (int mt = 0; mt < 2; ++mt)
                #pragma unroll
                for (int r = 0; r < 4; ++r) {
                    const float v = acc[mt][t][r] + bcol;
                    int lidx;
                    if (mode == 1)
                        lidx = (mt * 16 + quad * 4 + r) * 64 + t * 16 + li;
                    else if (mode == 3)
                        lidx = t * 512 + (li >> 3) * 256 + (mt * 16 + quad * 4 + r) * 8 + (li & 7);
                    else  // mode 4
                        lidx = (t >> 1) * 1024 + mt * 512 + (quad >> 1) * 256
                             + ((t & 1) * 16 + li) * 8 + (quad & 1) * 4 + r;
                    slab[lidx] = __float2bfloat16(v);
                }
        }
        __syncthreads();
        const int bb2 = m0 / L;
        const int i0  = m0 - bb2 * L;
        const int hh  = n0 >> 6;
        const int bh  = bb2 * 8 + hh;
        bf16* base;
        if (mode == 1) base = (bf16*)Cout + ((size_t)bh * L + i0) * 64;
        else           base = (bf16*)Cout + (size_t)bh * L * 64 + (size_t)(i0 >> 5) * 2048;
        #pragma unroll
        for (int s = 0; s < 4; ++s)
            *reinterpret_cast<bf16x8*>(base + s * 512 + lane * 8) =
                load8(&slab[s * 512 + lane * 8]);
    }
}

// Fused Q/K/V projections: 1280 blocks, XCD-grouped swizzle.
// id = g64*64 + nb*8 + rb  ->  row-tile myy = g64*8+rb, col-block nb.
// The 8 col-blocks of one row-tile share id%8 -> same XCD -> X in L2 once.
__global__ void proj_qkv(const bf16* __restrict__ qb, const bf16* __restrict__ kvb,
                         const bf16* __restrict__ Wq, const float* __restrict__ bq,
                         const bf16* __restrict__ Wk, const float* __restrict__ bk,
                         const bf16* __restrict__ Wv, const float* __restrict__ bv,
                         bf16* __restrict__ qp, bf16* __restrict__ kf,
                         bf16* __restrict__ vf) {
    __shared__ alignas(16) bf16 Ws[64 * 264];
    const int l   = blockIdx.x;              // 0..1279
    const int w   = l & 63;
    const int myy = (l >> 6) * 8 + (w & 7);  // 0..159
    const int nb  = w >> 3;                  // 0..7
    if (myy < 32)      proj_body(qb,  Wq, bq, qp, 1, 2048, myy,      nb, Ws);
    else if (myy < 96) proj_body(kvb, Wk, bk, kf, 3, 4096, myy - 32, nb, Ws);
    else               proj_body(kvb, Wv, bv, vf, 4, 4096, myy - 96, nb, Ws);
}

// Output projection: 256 blocks, same swizzle, fp32 out.
__global__ void proj_o(const bf16* __restrict__ op, const bf16* __restrict__ Wo,
                       const float* __restrict__ bo, float* __restrict__ out) {
    __shared__ alignas(16) bf16 Ws[64 * 264];
    const int l = blockIdx.x;                // 0..255
    const int w = l & 63;
    proj_body(op, Wo, bo, out, 0, 1, (l >> 6) * 8 + (w & 7), w >> 3, Ws);
}

// ---------------------------------------------------------------------------
// Barrier-free K-split flash attention, swapped-operand QK^T, no LDS.
// 512 blocks x 4 waves; wave owns 64 q-rows. XCD-grouped swizzle:
// id = a*64 + qt*8 + rb, g = a*8+rb = bh*4+sp -> the 8 qt-blocks sharing a
// (bh,sp) K/V slice (256KB) land on ONE XCD -> re-reads are L2 hits.
// K double-buffered (prefetch issued before softmax: ~350cy cover);
// V/gate single-buffered (load->use gap ~300cy). setprio around MFMA.
// ---------------------------------------------------------------------------
__global__ __launch_bounds__(256, 2)
void attn_kernel(const bf16* __restrict__ qp, const bf16* __restrict__ kf,
                 const bf16* __restrict__ vf, const float* __restrict__ g2,
                 float* __restrict__ Opart, float* __restrict__ lpart) {
    const int tid  = threadIdx.x;
    const int wave = tid >> 6;
    const int lane = tid & 63;
    const int ql   = lane & 31;
    const int hi   = lane >> 5;

    const int id = blockIdx.x;               // 0..511
    const int qt = (id >> 3) & 7;
    const int gg = ((id >> 6) << 3) | (id & 7);   // 0..63 = bh*4 + sp
    const int bh = gg >> 2;
    const int sp = gg & 3;
    const int b  = bh >> 3;
    const int q0 = qt * 256 + wave * 64;

    // Q B-fragments: bq[sub][ds]: lane holds Q[q0+sub*32+ql][ds*16 + hi*8 + j]
    bf16x8 bq[2][4];
    const bf16* qbp = qp + ((size_t)bh * 2048 + q0 + ql) * 64 + hi * 8;
    #pragma unroll
    for (int sub = 0; sub < 2; ++sub)
        #pragma unroll
        for (int ds = 0; ds < 4; ++ds)
            bq[sub][ds] = load8(qbp + sub * 2048 + ds * 16);

    f32x16 od[2][2];
    #pragma unroll
    for (int sub = 0; sub < 2; ++sub)
        #pragma unroll
        for (int t = 0; t < 2; ++t)
            #pragma unroll
            for (int r = 0; r < 16; ++r) od[sub][t][r] = 0.f;
    float lsum[2] = {0.f, 0.f};

    const bf16* kbase = kf + (size_t)bh * 262144 + (size_t)sp * 65536 + lane * 8;
    const bf16* vbase = vf + (size_t)bh * 262144 + (size_t)sp * 65536 + lane * 8;
    const float* gbase = g2 + (size_t)b * 4096 + sp * 1024 + hi * 4;

    const float SC = 0.18033688011112042f;   // log2(e) / 8

    bf16x8 ka0 = load8(kbase);
    bf16x8 ka1 = load8(kbase + 512);
    bf16x8 ka2 = load8(kbase + 1024);
    bf16x8 ka3 = load8(kbase + 1536);

    for (int kt = 0; kt < 32; ++kt) {
        // V fragments + gate for THIS tile (consumed after softmax / in softmax)
        const bf16* vp = vbase + (size_t)kt * 2048;
        bf16x8 bv00 = load8(vp);
        bf16x8 bv01 = load8(vp + 512);
        bf16x8 bv10 = load8(vp + 1024);
        bf16x8 bv11 = load8(vp + 1536);
        const float* gp = gbase + kt * 32;
        f32x4 gv0 = *(const f32x4*)(gp);
        f32x4 gv1 = *(const f32x4*)(gp + 8);
        f32x4 gv2 = *(const f32x4*)(gp + 16);
        f32x4 gv3 = *(const f32x4*)(gp + 24);

        // QK^T for both sub-tiles
        f32x16 s0, s1;
        #pragma unroll
        for (int r = 0; r < 16; ++r) { s0[r] = 0.f; s1[r] = 0.f; }
        __builtin_amdgcn_s_setprio(1);
        s0 = MFMA32(ka0, bq[0][0], s0);
        s0 = MFMA32(ka1, bq[0][1], s0);
        s0 = MFMA32(ka2, bq[0][2], s0);
        s0 = MFMA32(ka3, bq[0][3], s0);
        s1 = MFMA32(ka0, bq[1][0], s1);
        s1 = MFMA32(ka1, bq[1][1], s1);
        s1 = MFMA32(ka2, bq[1][2], s1);
        s1 = MFMA32(ka3, bq[1][3], s1);
        __builtin_amdgcn_s_setprio(0);

        // prefetch next K tile now: covered by softmax + PV (~350 cy)
        const int ktn = kt < 31 ? kt + 1 : 31;
        const bf16* kp_n = kbase + (size_t)ktn * 2048;
        bf16x8 kn0 = load8(kp_n);
        bf16x8 kn1 = load8(kp_n + 512);
        bf16x8 kn2 = load8(kp_n + 1024);
        bf16x8 kn3 = load8(kp_n + 1536);

        // in-register softmax (no-max): P = exp2(S*log2e/8 + log2gate)
        bf16x8 pa00, pa01, pa10, pa11;
        auto softmax = [&](const f32x16& sacc, float& lacc, bf16x8& plo, bf16x8& phi) {
            float p[16];
            #pragma unroll
            for (int r = 0; r < 16; ++r) {
                const float gl = (r < 4) ? gv0[r & 3] : (r < 8) ? gv1[r & 3]
                               : (r < 12) ? gv2[r & 3] : gv3[r & 3];
                p[r] = __builtin_amdgcn_exp2f(fmaf(sacc[r], SC, gl));
            }
            unsigned w[8];
            #pragma unroll
            for (int i = 0; i < 8; ++i)
                asm("v_cvt_pk_bf16_f32 %0, %1, %2"
                    : "=v"(w[i]) : "v"(p[2 * i]), "v"(p[2 * i + 1]));
            #pragma unroll
            for (int st = 1; st < 16; st <<= 1)
                #pragma unroll
                for (int r = 0; r < 16; r += 2 * st) p[r] += p[r + st];
            lacc += p[0];
            asm("v_permlane32_swap_b32 %0, %1" : "+v"(w[0]), "+v"(w[2]));
            asm("v_permlane32_swap_b32 %0, %1" : "+v"(w[1]), "+v"(w[3]));
            asm("v_permlane32_swap_b32 %0, %1" : "+v"(w[4]), "+v"(w[6]));
            asm("v_permlane32_swap_b32 %0, %1" : "+v"(w[5]), "+v"(w[7]));
            uint4v u0 = {w[0], w[1], w[2], w[3]};
            uint4v u1 = {w[4], w[5], w[6], w[7]};
            plo = __builtin_bit_cast(bf16x8, u0);
            phi = __builtin_bit_cast(bf16x8, u1);
        };
        softmax(s0, lsum[0], pa00, pa01);
        softmax(s1, lsum[1], pa10, pa11);

        // O += P @ V
        __builtin_amdgcn_s_setprio(1);
        od[0][0] = MFMA32(pa00, bv00, od[0][0]);
        od[0][0] = MFMA32(pa01, bv01, od[0][0]);
        od[0][1] = MFMA32(pa00, bv10, od[0][1]);
        od[0][1] = MFMA32(pa01, bv11, od[0][1]);
        od[1][0] = MFMA32(pa10, bv00, od[1][0]);
        od[1][0] = MFMA32(pa11, bv01, od[1][0]);
        od[1][1] = MFMA32(pa10, bv10, od[1][1]);
        od[1][1] = MFMA32(pa11, bv11, od[1][1]);
        __builtin_amdgcn_s_setprio(0);

        ka0 = kn0; ka1 = kn1; ka2 = kn2; ka3 = kn3;
    }

    float l0 = lsum[0] + __shfl_xor(lsum[0], 32);
    float l1 = lsum[1] + __shfl_xor(lsum[1], 32);

    float* ob = Opart + ((size_t)(bh * 2048 + q0) * 4 + sp) * 64;
    #pragma unroll
    for (int sub = 0; sub < 2; ++sub)
        #pragma unroll
        for (int t = 0; t < 2; ++t)
            #pragma unroll
            for (int r = 0; r < 16; ++r) {
                const int qq = sub * 32 + (r & 3) + 8 * (r >> 2) + hi * 4;
                ob[(size_t)qq * 256 + t * 32 + ql] = od[sub][t][r];
            }
    if (lane < 32) {
        lpart[((size_t)(bh * 2048 + q0 + lane)) * 4 + sp]      = l0;
        lpart[((size_t)(bh * 2048 + q0 + 32 + lane)) * 4 + sp] = l1;
    }
}

// ---------------------------------------------------------------------------
// Combine 4 K-split partials (plain sums; no max weights needed).
// ---------------------------------------------------------------------------
__global__ void attn_combine(const float* __restrict__ Opart,
                             const float* __restrict__ lpart,
                             bf16* __restrict__ op) {
    const int gidx = blockIdx.x * 256 + threadIdx.x;  // 0..131071
    const int row  = gidx >> 2;                        // bh*2048 + q
    const int c0   = (gidx & 3) * 16;

    float acc[16];
    #pragma unroll
    for (int j = 0; j < 16; ++j) acc[j] = 0.f;
    float L = 0.f;
    for (int s = 0; s < 4; ++s) {
        const float* src = Opart + ((size_t)row * 4 + s) * 64 + c0;
        const float4 v0 = reinterpret_cast<const float4*>(src)[0];
        const float4 v1 = reinterpret_cast<const float4*>(src)[1];
        const float4 v2 = reinterpret_cast<const float4*>(src)[2];
        const float4 v3 = reinterpret_cast<const float4*>(src)[3];
        acc[0] += v0.x; acc[1] += v0.y; acc[2]  += v0.z; acc[3]  += v0.w;
        acc[4] += v1.x; acc[5] += v1.y; acc[6]  += v1.z; acc[7]  += v1.w;
        acc[8] += v2.x; acc[9] += v2.y; acc[10] += v2.z; acc[11] += v2.w;
        acc[12] += v3.x; acc[13] += v3.y; acc[14] += v3.z; acc[15] += v3.w;
        L += lpart[(size_t)row * 4 + s];
    }
    const float invL = 1.0f / L;

    const int bh = row >> 11;
    const int q  = row & 2047;
    const int bb = bh >> 3;
    const int hh = bh & 7;
    bf16* dst = op + ((size_t)bb * 2048 + q) * 512 + hh * 64 + c0;
    bf16x8 r0, r1;
    #pragma unroll
    for (int j = 0; j < 8; ++j) {
        r0[j] = f2bf(acc[j] * invL);
        r1[j] = f2bf(acc[8 + j] * invL);
    }
    *reinterpret_cast<bf16x8*>(dst)     = r0;
    *reinterpret_cast<bf16x8*>(dst + 8) = r1;
}

// ---------------------------------------------------------------------------
extern "C" void kernel_launch(void* const* d_in, const int* in_sizes, int n_in,
                              void* d_out, int out_size, void* d_ws, size_t ws_size,
                              hipStream_t stream) {
    const float* q    = (const float*)d_in[0];
    const float* kv   = (const float*)d_in[1];
    const float* gate = (const float*)d_in[2];
    const int*   mask = (const int*)d_in[3];
    const float* Wq = (const float*)d_in[4];  const float* bq = (const float*)d_in[5];
    const float* Wk = (const float*)d_in[6];  const float* bk = (const float*)d_in[7];
    const float* Wv = (const float*)d_in[8];  const float* bv = (const float*)d_in[9];
    const float* Wo = (const float*)d_in[10]; const float* bo = (const float*)d_in[11];
    float* out = (float*)d_out;

    char* ws = (char*)d_ws;
    float* g2  = (float*)ws;
    bf16* Wqb  = (bf16*)(ws + (1u  << 20));
    bf16* Wkb  = (bf16*)(ws + (1u  << 20) + (512u << 10));
    bf16* Wvb  = (bf16*)(ws + (2u  << 20));
    bf16* Wob  = (bf16*)(ws + (2u  << 20) + (512u << 10));
    bf16* qb   = (bf16*)(ws + (3u  << 20));
    bf16* kvb  = (bf16*)(ws + (7u  << 20));
    bf16* qp   = (bf16*)(ws + (15u << 20));
    bf16* kf   = (bf16*)(ws + (19u << 20));
    bf16* vf   = (bf16*)(ws + (27u << 20));
    bf16* op   = (bf16*)(ws + (35u << 20));
    float* Opart = (float*)(ws + (39u << 20));
    float* lpart = (float*)(ws + (71u << 20));

    cvt_all<<<7176, 256, 0, stream>>>(q, kv, Wq, Wk, Wv, Wo, gate, mask,
                                      qb, kvb, Wqb, Wkb, Wvb, Wob, g2);

    proj_qkv<<<1280, 256, 0, stream>>>(qb, kvb, Wqb, bq, Wkb, bk,
                                       Wvb, bv, qp, kf, vf);

    attn_kernel<<<512, 256, 0, stream>>>(qp, kf, vf, g2, Opart, lpart);
    attn_combine<<<512, 256, 0, stream>>>(Opart, lpart, op);

    proj_o<<<256, 256, 0, stream>>>(op, Wob, bo, out);
}